// Round 6
// baseline (5005.748 us; speedup 1.0000x reference)
//
#include <hip/hip_runtime.h>
#include <stdint.h>

#define N_ROWS 32768
#define D_DIM  512
#define K_CODES 4096

// ---- workspace layout (bytes) ----
#define WS_KEYS   0          // u64[32768]            -> 262144
#define WS_XNORM  262144     // f32[32768]            -> 393216
#define WS_ENORM  393216     // f32[4096]             -> 409600
#define WS_PART   409600     // f32[16384]            -> 475136
#define WS_EMBT   475136     // f32[4096*512] = 8 MiB

typedef __attribute__((address_space(3))) unsigned int lds_uint;
typedef __attribute__((address_space(1))) const unsigned int glob_uint;
__device__ __forceinline__ void async_cp16(const void* g, void* l) {
    // 16B per lane, LDS dest = wave-uniform base + lane*16
    __builtin_amdgcn_global_load_lds((glob_uint*)g, (lds_uint*)l, 16, 0, 0);
}

__global__ __launch_bounds__(256) void k_init(unsigned long long* keys) {
    int t = blockIdx.x * 256 + threadIdx.x;
    if (t < N_ROWS) keys[t] = ~0ull;
}

// emb [D][K] -> embT [K][D] (bitwise copy, for coalesced gather)
__global__ __launch_bounds__(256) void k_transpose(const float* __restrict__ emb,
                                                   float* __restrict__ embT) {
    __shared__ float tile[64][65];
    int k0 = blockIdx.x * 64;
    int d0 = blockIdx.y * 64;
    int tid = threadIdx.x;
    int kk = tid & 63;
    int dd = tid >> 6;
#pragma unroll
    for (int r = 0; r < 16; ++r) {
        int d = dd + r * 4;
        tile[d][kk] = emb[(size_t)(d0 + d) * K_CODES + k0 + kk];
    }
    __syncthreads();
    int dOff = tid & 63;
    int kBase = tid >> 6;
#pragma unroll
    for (int r = 0; r < 16; ++r) {
        int k = kBase + r * 4;
        embT[(size_t)(k0 + k) * D_DIM + d0 + dOff] = tile[dOff][k];
    }
}

// xnorm = np.sum(x*x, axis=1), bitwise (numpy pairwise + AVX512 tree)
__global__ __launch_bounds__(256) void k_xnorm(const float* __restrict__ x,
                                               float* __restrict__ xnorm) {
#pragma clang fp contract(off)
    int lane = threadIdx.x & 63;
    int l = lane & 15;
    int rowInWave = lane >> 4;
    int wave = blockIdx.x * 4 + (threadIdx.x >> 6);
    int row = wave * 4 + rowInWave;
    const float* xr = x + (size_t)row * D_DIM;
    float B[4];
#pragma unroll
    for (int b = 0; b < 4; ++b) {
        const float* a = xr + b * 128;
        float r[8];
#pragma unroll
        for (int j = 0; j < 8; ++j) {
            float v = a[j * 16 + l];
            r[j] = v * v;
        }
        float V = ((r[0] + r[1]) + (r[2] + r[3])) + ((r[4] + r[5]) + (r[6] + r[7]));
        float T1 = V + __shfl_xor(V, 8);
        float T2 = T1 + __shfl_xor(T1, 4);
        float U  = T2 + __shfl_xor(T2, 2);
        B[b] = U + __shfl_xor(U, 1);
    }
    float total = (B[0] + B[1]) + (B[2] + B[3]);
    if (l == 0) xnorm[row] = total;
}

// enorm = np.sum(e*e, axis=0): strictly sequential over d, no fma
__global__ __launch_bounds__(256) void k_enorm(const float* __restrict__ emb,
                                               float* __restrict__ enorm) {
#pragma clang fp contract(off)
    int k = blockIdx.x * 256 + threadIdx.x;
    float v = emb[k];
    float acc = v * v;
    for (int d = 1; d < D_DIM; ++d) {
        float u = emb[(size_t)d * K_CODES + k];
        acc = acc + u * u;
    }
    enorm[k] = acc;
}

// Fused GEMM + argmin. 256x128 block tile, 256 threads, 16x8 micro-tile
// (0.375 LDS-bytes/FLOP -> VALU-bound, not LDS-bound). A tile in LDS with
// XOR-d swizzle (conflict-free reads, 2-way-free writes); B double-buffered
// via global_load_lds issued right after the barrier. Per-(row,col) fp32
// FMA chain strictly d-ascending -> bitwise equal to numpy sgemm chain.
__global__ __launch_bounds__(256, 2) void k_argmin(const float* __restrict__ x,
                                                   const float* __restrict__ emb,
                                                   const float* __restrict__ xnorm,
                                                   const float* __restrict__ enorm,
                                                   unsigned long long* __restrict__ keys) {
    // As element (d,m): word d*256 + 64*(m>>6) + ((((m>>2)&15) ^ d)<<2) + (m&3)
    __shared__ float As[16 * 256];   // 16 KiB
    __shared__ float Bs[2][16 * 128];  // 16 KiB
    const int tid = threadIdx.x;
    const int tx = tid & 15;   // col group: cols {4tx..+3, 64+4tx..+3}
    const int ty = tid >> 4;   // row group: rows {64s + 4ty..+3, s=0..3}
    const int rowBase = blockIdx.x * 256;
    const int colBase = blockIdx.y * 128;
    const int lane = tid & 63;
    const int wv = tid >> 6;

    float acc[16][8];
#pragma unroll
    for (int j = 0; j < 16; ++j)
#pragma unroll
        for (int i = 0; i < 8; ++i) acc[j][i] = 0.f;

    // A staging: 4 passes; pass p: row = 64p + (tid>>2), d-quad = tid&3
    const int q = tid & 3;
    const int rr = tid >> 2;       // 0..63
    const int g0 = rr >> 2;        // 0..15
    const int cc0 = rr & 3;        // m&3
    const float* gA[4];
#pragma unroll
    for (int p = 0; p < 4; ++p)
        gA[p] = x + (size_t)(rowBase + 64 * p + rr) * D_DIM + 4 * q;

    // B async staging: wave wv covers d rows {2wv,2wv+1} and {8+2wv,8+2wv+1}
    const int bd0 = 2 * wv;
    const float* gBbase = emb + (size_t)(bd0 + (lane >> 5)) * K_CODES + colBase + (lane & 31) * 4;

    // prime: async B chunk 0, prefetch A chunk 0
    async_cp16(gBbase, &Bs[0][bd0 * 128]);
    async_cp16(gBbase + (size_t)8 * K_CODES, &Bs[0][(8 + bd0) * 128]);
    float4 pa[4];
#pragma unroll
    for (int p = 0; p < 4; ++p) pa[p] = *(const float4*)gA[p];

    for (int c = 0; c < 32; ++c) {
        __syncthreads();  // all waves done reading As / other B buffer
        // store A tile (swizzled)
#pragma unroll
        for (int p = 0; p < 4; ++p) {
            const float v[4] = {pa[p].x, pa[p].y, pa[p].z, pa[p].w};
#pragma unroll
            for (int i = 0; i < 4; ++i) {
                int d = 4 * q + i;
                As[d * 256 + 64 * p + ((g0 ^ d) << 2) + cc0] = v[i];
            }
        }
        __syncthreads();  // As visible; async B for this chunk already landed
        if (c + 1 < 32) {
            const int dn = (c + 1) * 16;
            float* bdst = &Bs[(c + 1) & 1][0];
            async_cp16(gBbase + (size_t)dn * K_CODES, bdst + bd0 * 128);
            async_cp16(gBbase + (size_t)(dn + 8) * K_CODES, bdst + (8 + bd0) * 128);
#pragma unroll
            for (int p = 0; p < 4; ++p) pa[p] = *(const float4*)(gA[p] + dn);
        }
        const float* B = &Bs[c & 1][0];
#pragma unroll
        for (int d = 0; d < 16; ++d) {
            const int aoff = d * 256 + ((ty ^ d) << 2);
            const float4 a0 = *(const float4*)&As[aoff];
            const float4 a1 = *(const float4*)&As[aoff + 64];
            const float4 a2 = *(const float4*)&As[aoff + 128];
            const float4 a3 = *(const float4*)&As[aoff + 192];
            const float4 b0 = *(const float4*)&B[d * 128 + (tx << 2)];
            const float4 b1 = *(const float4*)&B[d * 128 + (tx << 2) + 64];
            const float av[16] = {a0.x, a0.y, a0.z, a0.w, a1.x, a1.y, a1.z, a1.w,
                                  a2.x, a2.y, a2.z, a2.w, a3.x, a3.y, a3.z, a3.w};
            const float bv[8] = {b0.x, b0.y, b0.z, b0.w, b1.x, b1.y, b1.z, b1.w};
#pragma unroll
            for (int j = 0; j < 16; ++j)
#pragma unroll
                for (int i = 0; i < 8; ++i)
                    acc[j][i] = fmaf(av[j], bv[i], acc[j][i]);
        }
    }

    // epilogue: d = fl(fl(xnorm+enorm) - 2*acc); pack into orderable key
    float en[8];
    *(float4*)&en[0] = *(const float4*)&enorm[colBase + 4 * tx];
    *(float4*)&en[4] = *(const float4*)&enorm[colBase + 64 + 4 * tx];
#pragma unroll
    for (int j = 0; j < 16; ++j) {
        int row = rowBase + 64 * (j >> 2) + 4 * ty + (j & 3);
        float A = xnorm[row];
        unsigned long long best = ~0ull;
#pragma unroll
        for (int i = 0; i < 8; ++i) {
            int col = colBase + ((i < 4) ? (4 * tx + i) : (64 + 4 * tx + (i - 4)));
            float t1 = A + en[i];
            float dd = t1 - 2.0f * acc[j][i];  // 2*acc exact; single rounding
            unsigned u = __float_as_uint(dd);
            u = (u & 0x80000000u) ? ~u : (u | 0x80000000u);
            unsigned long long key = ((unsigned long long)u << 32) | (unsigned)col;
            best = key < best ? key : best;
        }
#pragma unroll
        for (int off = 8; off > 0; off >>= 1) {
            unsigned long long other = __shfl_xor(best, off, 16);
            best = other < best ? other : best;
        }
        if (tx == 0) atomicMin(&keys[row], best);
    }
}

// gather codes, STE output fl(x + fl(q-x)), per-block f32 loss partial
__global__ __launch_bounds__(256) void k_gather(const float* __restrict__ x,
                                                const float* __restrict__ embSrc,
                                                int embIsT,
                                                const unsigned long long* __restrict__ keys,
                                                float* __restrict__ out,
                                                float* __restrict__ partial) {
#pragma clang fp contract(off)
    int tid = threadIdx.x;
    int row = blockIdx.x * 2 + (tid >> 7);
    int d = (tid & 127) * 4;
    int idx = (int)(keys[row] & 0xFFFFFFFFull);
    float4 q;
    if (embIsT) {
        q = *(const float4*)&embSrc[(size_t)idx * D_DIM + d];
    } else {
        q.x = embSrc[(size_t)(d + 0) * K_CODES + idx];
        q.y = embSrc[(size_t)(d + 1) * K_CODES + idx];
        q.z = embSrc[(size_t)(d + 2) * K_CODES + idx];
        q.w = embSrc[(size_t)(d + 3) * K_CODES + idx];
    }
    float4 xv = *(const float4*)&x[(size_t)row * D_DIM + d];
    float d0 = q.x - xv.x, d1 = q.y - xv.y, d2 = q.z - xv.z, d3 = q.w - xv.w;
    float4 o;
    o.x = xv.x + d0; o.y = xv.y + d1; o.z = xv.z + d2; o.w = xv.w + d3;
    *(float4*)&out[(size_t)row * D_DIM + d] = o;
    float s = (d0 * d0 + d1 * d1) + (d2 * d2 + d3 * d3);
#pragma unroll
    for (int off = 32; off > 0; off >>= 1) s += __shfl_xor(s, off, 64);
    __shared__ float wsum[4];
    int lane = tid & 63, wvv = tid >> 6;
    if (lane == 0) wsum[wvv] = s;
    __syncthreads();
    if (tid == 0) partial[blockIdx.x] = (wsum[0] + wsum[1]) + (wsum[2] + wsum[3]);
}

__global__ __launch_bounds__(256) void k_reduce(const float* __restrict__ partial,
                                                float* __restrict__ out) {
    float s = 0.f;
    for (int i = threadIdx.x; i < 16384; i += 256) s += partial[i];
#pragma unroll
    for (int off = 32; off > 0; off >>= 1) s += __shfl_xor(s, off, 64);
    __shared__ float wsum[4];
    int lane = threadIdx.x & 63, wv = threadIdx.x >> 6;
    if (lane == 0) wsum[wv] = s;
    __syncthreads();
    if (threadIdx.x == 0) {
        float t = (wsum[0] + wsum[1]) + (wsum[2] + wsum[3]);
        float m = t / 16777216.f;               // mean((q-x)^2), N*D = 2^24
        out[(size_t)N_ROWS * D_DIM] = 0.25f * m + m;  // beta*m + m
    }
}

extern "C" void kernel_launch(void* const* d_in, const int* in_sizes, int n_in,
                              void* d_out, int out_size, void* d_ws, size_t ws_size,
                              hipStream_t stream) {
    const float* x = (const float*)d_in[0];
    const float* emb = (const float*)d_in[1];
    float* out = (float*)d_out;
    char* ws = (char*)d_ws;

    unsigned long long* keys = (unsigned long long*)(ws + WS_KEYS);
    float* xnorm = (float*)(ws + WS_XNORM);
    float* enorm = (float*)(ws + WS_ENORM);
    float* partial = (float*)(ws + WS_PART);
    float* embT = (float*)(ws + WS_EMBT);
    size_t need = WS_EMBT + (size_t)K_CODES * D_DIM * sizeof(float);
    int useT = (ws_size >= need) ? 1 : 0;

    hipLaunchKernelGGL(k_init, dim3(128), dim3(256), 0, stream, keys);
    if (useT)
        hipLaunchKernelGGL(k_transpose, dim3(K_CODES / 64, D_DIM / 64), dim3(256), 0, stream,
                           emb, embT);
    hipLaunchKernelGGL(k_xnorm, dim3(N_ROWS / 16), dim3(256), 0, stream, x, xnorm);
    hipLaunchKernelGGL(k_enorm, dim3(K_CODES / 256), dim3(256), 0, stream, emb, enorm);
    hipLaunchKernelGGL(k_argmin, dim3(N_ROWS / 256, K_CODES / 128), dim3(256), 0, stream,
                       x, emb, xnorm, enorm, keys);
    hipLaunchKernelGGL(k_gather, dim3(N_ROWS / 2), dim3(256), 0, stream,
                       x, useT ? embT : emb, useT, keys, out, partial);
    hipLaunchKernelGGL(k_reduce, dim3(1), dim3(256), 0, stream, partial, out);
}